// Round 5
// baseline (73.772 us; speedup 1.0000x reference)
//
#include <hip/hip_runtime.h>
#include <hip/hip_bf16.h>

#define NB    16
#define CIN   64
#define COUT  64
#define HIN   66
#define WIN   66
#define HOUT  64
#define WOUT  64
#define KK    9
#define NXCD  8

typedef __attribute__((ext_vector_type(8))) short bf16x8;
typedef __attribute__((ext_vector_type(4))) float f32x4;

static __device__ __forceinline__ unsigned int f2bf_u(float f) {
    union { float f; unsigned int u; } x; x.f = f;
    return (x.u + 0x7fff + ((x.u >> 16) & 1)) >> 16;      // RNE
}

// ---------------- repack: NCHW -> NHWC f32 ----------------
__global__ __launch_bounds__(256) void repack_inp(const float* __restrict__ in,
                                                  float* __restrict__ nhwc) {
    int b = blockIdx.x;
    int n = b / HIN, y = b % HIN;
    __shared__ float buf[CIN * 67];
    const float* src = in + (size_t)(n * CIN) * HIN * WIN + y * WIN;
    for (int i = threadIdx.x; i < CIN * WIN; i += 256) {
        int c = i / WIN, x = i - c * WIN;
        buf[c * 67 + x] = src[c * (HIN * WIN) + x];
    }
    __syncthreads();
    float* dst = nhwc + (size_t)((n * HIN + y) * WIN) * CIN;
    for (int i = threadIdx.x; i < CIN * WIN; i += 256) {
        int x = i >> 6, c = i & 63;
        dst[x * CIN + c] = buf[c * 67 + x];
    }
}

// ---------------- repack: weights -> LINEAR bf16 [kb][cout][klocal] ----------------
// klocal = (tap-3kb)*64 + cin;  byte = kb*24576 + cout*384 + klocal*2.
// B-fragment for (ks,h): 16B at cout*384 + h*16 + ks*64 — constant offsets, global reads.
__global__ __launch_bounds__(256) void repack_wL(const float* __restrict__ w,
                                                 unsigned short* __restrict__ wL) {
    int i = blockIdx.x * 256 + threadIdx.x;
    if (i >= 3 * 64 * 192) return;
    int kb   = i / 12288;
    int rem  = i - kb * 12288;
    int cout = rem / 192;
    int kl   = rem - cout * 192;
    int tap  = kb * 3 + (kl >> 6);
    int cin  = kl & 63;
    wL[i] = (unsigned short)f2bf_u(w[(cout * CIN + cin) * KK + tap]);
}

// ---------------- main: implicit-GEMM deformable conv via MFMA ----------------
__global__ __launch_bounds__(256, 4) void dconv4(const float* __restrict__ nhwc,
                                                 const float* __restrict__ off,
                                                 const unsigned short* __restrict__ wL,
                                                 float* __restrict__ out) {
    __shared__ __align__(16) char sm[36096];
    char*  smS = sm;                                   // 24576: sampled tile (swizzled)
    int*   sA  = (int*)(sm + 24576);                   // 576 packed addrs
    float* sWf = (float*)(sm + 26880);                 // 576*4 bilinear weights

    const int tid  = threadIdx.x;
    const int lane = tid & 63;
    const int wv   = tid >> 6;
    const int p0 = blockIdx.x;
    const int logical = (p0 & (NXCD - 1)) * (NB * HOUT / NXCD) + (p0 >> 3);
    const int n  = logical >> 6;
    const int ho = logical & 63;

    const float* nh_n  = nhwc + (size_t)n * (HIN * WIN * CIN);
    const float* off_n = off + (size_t)n * (2 * KK * HOUT * WOUT) + ho * WOUT;

    // ---- S1: bilinear meta per (tap,wo): packed addr/steps + 4 f32 weights ----
    for (int q = tid; q < KK * 64; q += 256) {
        int k  = q >> 6;
        int wo = q & 63;
        float dy = off_n[(2 * k) * (HOUT * WOUT) + wo];
        float dx = off_n[(2 * k + 1) * (HOUT * WOUT) + wo];
        int kh = (k * 171) >> 9;                       // k/3 for k<9
        int kw = k - 3 * kh;
        float py = (float)(ho + kh) + dy;
        float px = (float)(wo + kw) + dx;
        float y0f = floorf(py), x0f = floorf(px);
        float fy = py - y0f, fx = px - x0f;
        int y0 = (int)y0f, x0 = (int)x0f;
        int y1 = y0 + 1,   x1 = x0 + 1;
        float vy0 = (y0 >= 0 && y0 < HIN) ? 1.f : 0.f;
        float vy1 = (y1 >= 0 && y1 < HIN) ? 1.f : 0.f;
        float vx0 = (x0 >= 0 && x0 < WIN) ? 1.f : 0.f;
        float vx1 = (x1 >= 0 && x1 < WIN) ? 1.f : 0.f;
        int y0c = min(max(y0, 0), HIN - 1), y1c = min(max(y1, 0), HIN - 1);
        int x0c = min(max(x0, 0), WIN - 1), x1c = min(max(x1, 0), WIN - 1);
        int a00 = (y0c * WIN + x0c) * CIN;             // <2^19
        int sx  = x1c - x0c;                           // 0/1
        int sy  = y1c - y0c;                           // 0/1
        sA[q] = a00 | (sx << 20) | (sy << 21);
        sWf[q * 4 + 0] = (1.f - fy) * (1.f - fx) * vy0 * vx0;
        sWf[q * 4 + 1] = (1.f - fy) * fx         * vy0 * vx1;
        sWf[q * 4 + 2] = fy * (1.f - fx)         * vy1 * vx0;
        sWf[q * 4 + 3] = fy * fx                 * vy1 * vx1;
    }
    __syncthreads();

    f32x4 acc[4];
#pragma unroll
    for (int ct = 0; ct < 4; ++ct) acc[ct] = (f32x4){0.f, 0.f, 0.f, 0.f};

    const int c0   = (lane & 15) * 4;                  // 4 channels per lane
    const int grp  = lane >> 4;                        // 4 (tap,wo) pairs per wave-iter
    const int row  = 16 * wv + (lane & 15);            // GEMM A row (pixel)
    const int h    = lane >> 4;

#pragma unroll 1
    for (int kb = 0; kb < 3; ++kb) {
        // ---- gather: 192 pairs, float4 per lane (16 lanes per pair) ----
#pragma unroll 2
        for (int it = 0; it < 12; ++it) {
            int p  = wv * 48 + it * 4 + grp;
            int q  = kb * 192 + p;
            int av = sA[q];                            // 16-lane broadcast
            float4 wt = *(const float4*)&sWf[q * 4];
            int a00 = (av & 0xFFFFF) + c0;
            int dxs = (av >> 14) & 64;                 // +CIN if x-step
            int dys = ((av >> 21) & 1) * (WIN * CIN);
            float4 g00 = *(const float4*)(nh_n + a00);
            float4 g01 = *(const float4*)(nh_n + a00 + dxs);
            float4 g10 = *(const float4*)(nh_n + a00 + dys);
            float4 g11 = *(const float4*)(nh_n + a00 + dys + dxs);
            float v0 = wt.x * g00.x + wt.y * g01.x + wt.z * g10.x + wt.w * g11.x;
            float v1 = wt.x * g00.y + wt.y * g01.y + wt.z * g10.y + wt.w * g11.y;
            float v2 = wt.x * g00.z + wt.y * g01.z + wt.z * g10.z + wt.w * g11.z;
            float v3 = wt.x * g00.w + wt.y * g01.w + wt.z * g10.w + wt.w * g11.w;
            unsigned int u0 = f2bf_u(v0) | (f2bf_u(v1) << 16);
            unsigned int u1 = f2bf_u(v2) | (f2bf_u(v3) << 16);
            int k3 = p >> 6, wo = p & 63;
            int slot = (k3 * 8 + (c0 >> 3)) ^ (wo & 7);
            *(int2*)(smS + wo * 384 + (slot << 4) + (c0 & 7) * 2) = make_int2(u0, u1);
        }
        __syncthreads();

        // ---- GEMM: A from LDS (swizzled), B straight from global (L1/L2-hot) ----
        const char* wb = (const char*)wL + kb * 24576 + (lane & 15) * 384 + h * 16;
#pragma unroll
        for (int ks = 0; ks < 6; ++ks) {
            int aslot = (ks * 4 + h) ^ (row & 7);
            bf16x8 af = *(const bf16x8*)(smS + row * 384 + (aslot << 4));
#pragma unroll
            for (int ct = 0; ct < 4; ++ct) {
                bf16x8 bf = *(const bf16x8*)(wb + ct * 6144 + ks * 64);
                acc[ct] = __builtin_amdgcn_mfma_f32_16x16x32_bf16(af, bf, acc[ct], 0, 0, 0);
            }
        }
        __syncthreads();                               // smS reused next kb
    }

    // ---- epilogue: transpose through LDS for coalesced stores ----
    float* red = (float*)sm;                           // [64 couts][65] = 16640 B
#pragma unroll
    for (int ct = 0; ct < 4; ++ct)
#pragma unroll
        for (int r = 0; r < 4; ++r)
            red[(16 * ct + (lane & 15)) * 65 + (16 * wv + (lane >> 4) * 4 + r)] = acc[ct][r];
    __syncthreads();
    float* op = out + (size_t)(n * COUT) * (HOUT * WOUT) + ho * WOUT + lane;
#pragma unroll
    for (int j = 0; j < 16; ++j) {
        int co = wv * 16 + j;
        op[(size_t)co * (HOUT * WOUT)] = red[co * 65 + lane];
    }
}

// ---------------- fallback (R2 path) if ws too small ----------------
__global__ __launch_bounds__(256) void repack_w_kernel(const float* __restrict__ w,
                                                       float* __restrict__ wT) {
    int i = blockIdx.x * 256 + threadIdx.x;
    if (i >= KK * CIN * COUT) return;
    int co = i & 63; int t = i >> 6;
    int c = t & 63;  int k = t >> 6;
    wT[i] = w[(co * CIN + c) * KK + k];
}

__global__ __launch_bounds__(256) void dconv_kernel(const float* __restrict__ inp,
                                                    const float* __restrict__ off,
                                                    const float* __restrict__ wT,
                                                    float* __restrict__ out) {
    const int tid = threadIdx.x;
    const int wo  = tid & 63;
    const int g   = tid >> 6;
    const int p   = blockIdx.x;
    const int logical = (p & (NXCD - 1)) * (NB * HOUT / NXCD) + (p >> 3);
    const int n   = logical >> 6;
    const int ho  = logical & 63;
    const int cbase = __builtin_amdgcn_readfirstlane(g << 4);
    float acc[COUT];
#pragma unroll
    for (int i = 0; i < COUT; ++i) acc[i] = 0.f;
    const float* inp_n = inp + n * (CIN * HIN * WIN);
    const float* off_p = off + ((n * (2 * KK)) * HOUT + ho) * WOUT + wo;
#pragma unroll 1
    for (int k = 0; k < KK; ++k) {
        float dy = off_p[(2 * k) * (HOUT * WOUT)];
        float dx = off_p[(2 * k + 1) * (HOUT * WOUT)];
        float py = (float)(ho + k / 3) + dy;
        float px = (float)(wo + k % 3) + dx;
        float y0f = floorf(py), x0f = floorf(px);
        float fy = py - y0f, fx = px - x0f;
        int y0 = (int)y0f, x0 = (int)x0f;
        int y1 = y0 + 1,   x1 = x0 + 1;
        float vy0 = (y0 >= 0 && y0 < HIN) ? 1.f : 0.f;
        float vy1 = (y1 >= 0 && y1 < HIN) ? 1.f : 0.f;
        float vx0 = (x0 >= 0 && x0 < WIN) ? 1.f : 0.f;
        float vx1 = (x1 >= 0 && x1 < WIN) ? 1.f : 0.f;
        int y0c = min(max(y0, 0), HIN - 1), y1c = min(max(y1, 0), HIN - 1);
        int x0c = min(max(x0, 0), WIN - 1), x1c = min(max(x1, 0), WIN - 1);
        int o00 = y0c * WIN + x0c, o01 = y0c * WIN + x1c;
        int o10 = y1c * WIN + x0c, o11 = y1c * WIN + x1c;
        float w00 = (1.f - fy) * (1.f - fx) * vy0 * vx0;
        float w01 = (1.f - fy) * fx * vy0 * vx1;
        float w10 = fy * (1.f - fx) * vy1 * vx0;
        float w11 = fy * fx * vy1 * vx1;
        const float* pc   = inp_n + cbase * (HIN * WIN);
        const float* wrow = wT + ((k * CIN + cbase) << 6);
#pragma unroll 4
        for (int c = 0; c < 16; ++c) {
            float v = w00 * pc[o00] + w01 * pc[o01] + w10 * pc[o10] + w11 * pc[o11];
#pragma unroll
            for (int co = 0; co < COUT; ++co) acc[co] = fmaf(v, wrow[co], acc[co]);
            pc += HIN * WIN; wrow += COUT;
        }
    }
    __shared__ float redf[COUT * WOUT];
    for (int i = tid; i < COUT * WOUT; i += 256) redf[i] = 0.f;
    __syncthreads();
#pragma unroll
    for (int co = 0; co < COUT; ++co) atomicAdd(&redf[co * WOUT + wo], acc[co]);
    __syncthreads();
    float* out_p = out + (n * COUT * HOUT + ho) * WOUT;
    for (int i = tid; i < COUT * WOUT; i += 256) {
        int co = i >> 6, w2 = i & 63;
        out_p[co * (HOUT * WOUT) + w2] = redf[i];
    }
}

extern "C" void kernel_launch(void* const* d_in, const int* in_sizes, int n_in,
                              void* d_out, int out_size, void* d_ws, size_t ws_size,
                              hipStream_t stream) {
    const float* inp = (const float*)d_in[0];
    const float* off = (const float*)d_in[1];
    const float* w   = (const float*)d_in[2];
    float* out = (float*)d_out;

    const size_t nhwc_bytes = (size_t)NB * HIN * WIN * CIN * sizeof(float); // 17,842,176
    const size_t wL_bytes   = 3 * 24576;                                    // 73,728

    if (ws_size >= nhwc_bytes + wL_bytes) {
        float* nhwc = (float*)d_ws;
        unsigned short* wL = (unsigned short*)((char*)d_ws + nhwc_bytes);
        repack_wL<<<(3 * 64 * 192 + 255) / 256, 256, 0, stream>>>(w, wL);
        repack_inp<<<NB * HIN, 256, 0, stream>>>(inp, nhwc);
        dconv4<<<NB * HOUT, 256, 0, stream>>>(nhwc, off, wL, out);
    } else {
        float* wT = (float*)d_ws;
        repack_w_kernel<<<(KK * CIN * COUT + 255) / 256, 256, 0, stream>>>(w, wT);
        dconv_kernel<<<NB * HOUT, 256, 0, stream>>>(inp, off, wT, out);
    }
}

// Round 6
// 41.793 us; speedup vs baseline: 1.7652x; 1.7652x over previous
//
#include <hip/hip_runtime.h>
#include <hip/hip_bf16.h>

#define NB    16
#define CIN   64
#define COUT  64
#define HIN   66
#define WIN   66
#define HOUT  64
#define WOUT  64
#define KK    9
#define NXCD  8

typedef __attribute__((ext_vector_type(8))) short bf16x8;
typedef __attribute__((ext_vector_type(4))) float f32x4;

static __device__ __forceinline__ unsigned int f2bf_u(float f) {
    union { float f; unsigned int u; } x; x.f = f;
    return (x.u + 0x7fff + ((x.u >> 16) & 1)) >> 16;      // RNE
}

static __device__ __forceinline__ unsigned int blend_pair(unsigned int d00, unsigned int d01,
                                                          unsigned int d10, unsigned int d11,
                                                          float4 wt) {
    float lo = wt.x * __uint_as_float(d00 << 16) + wt.y * __uint_as_float(d01 << 16)
             + wt.z * __uint_as_float(d10 << 16) + wt.w * __uint_as_float(d11 << 16);
    float hi = wt.x * __uint_as_float(d00 & 0xFFFF0000u) + wt.y * __uint_as_float(d01 & 0xFFFF0000u)
             + wt.z * __uint_as_float(d10 & 0xFFFF0000u) + wt.w * __uint_as_float(d11 & 0xFFFF0000u);
    return f2bf_u(lo) | (f2bf_u(hi) << 16);
}

// ---------------- repack: NCHW f32 -> NHWC bf16 ----------------
__global__ __launch_bounds__(256) void repack_inp_bf(const float* __restrict__ in,
                                                     unsigned short* __restrict__ nhwc) {
    int b = blockIdx.x;
    int n = b / HIN, y = b % HIN;
    __shared__ float buf[CIN * 67];
    const float* src = in + (size_t)(n * CIN) * HIN * WIN + y * WIN;
    for (int i = threadIdx.x; i < CIN * WIN; i += 256) {
        int c = i / WIN, x = i - c * WIN;
        buf[c * 67 + x] = src[c * (HIN * WIN) + x];
    }
    __syncthreads();
    unsigned short* dst = nhwc + (size_t)((n * HIN + y) * WIN) * CIN;
    for (int i = threadIdx.x; i < CIN * WIN; i += 256) {
        int x = i >> 6, c = i & 63;
        dst[x * CIN + c] = (unsigned short)f2bf_u(buf[c * 67 + x]);
    }
}

// ---------------- repack: weights -> fragment-major bf16 ----------------
// wF[((ct*18 + ksg)*64 + lane)*8 + j]: the exact B-fragment image.
// lane = (c = lane&15, h = lane>>4); ksg = kb*6+ks; klocal = ks*32 + h*8 + j;
// tap = kb*3 + klocal>>6; cin = klocal&63; cout = ct*16 + c.
__global__ __launch_bounds__(256) void repack_wF(const float* __restrict__ w,
                                                 unsigned short* __restrict__ wF) {
    int i = blockIdx.x * 256 + threadIdx.x;
    if (i >= 4 * 18 * 64 * 8) return;
    int j    = i & 7;
    int t    = i >> 3;
    int lane = t & 63;  t >>= 6;
    int ksg  = t % 18;
    int ct   = t / 18;
    int kb = ksg / 6, ks = ksg % 6;
    int klocal = ks * 32 + (lane >> 4) * 8 + j;
    int tap = kb * 3 + (klocal >> 6);
    int cin = klocal & 63;
    int cout = ct * 16 + (lane & 15);
    wF[i] = (unsigned short)f2bf_u(w[(cout * CIN + cin) * KK + tap]);
}

// ---------------- main: implicit-GEMM deformable conv via MFMA ----------------
__global__ __launch_bounds__(256, 3) void dconv5(const unsigned short* __restrict__ nhwc,
                                                 const float* __restrict__ off,
                                                 const unsigned short* __restrict__ wF,
                                                 float* __restrict__ out) {
    __shared__ __align__(16) char sm[36096];
    char*  smS = sm;                                   // 24576: sampled tile (swizzled)
    int*   sA  = (int*)(sm + 24576);                   // 576 packed addrs
    float* sWf = (float*)(sm + 26880);                 // 576*4 bilinear weights

    const int tid  = threadIdx.x;
    const int lane = tid & 63;
    const int wv   = tid >> 6;
    const int p0 = blockIdx.x;
    const int logical = (p0 & (NXCD - 1)) * (NB * HOUT / NXCD) + (p0 >> 3);
    const int n  = logical >> 6;
    const int ho = logical & 63;

    const unsigned short* nh = nhwc + (size_t)n * (HIN * WIN * CIN);
    const float* off_n = off + (size_t)n * (2 * KK * HOUT * WOUT) + ho * WOUT;

    // ---- S1: bilinear meta per (tap,wo): packed addr/steps + 4 f32 weights ----
    for (int q = tid; q < KK * 64; q += 256) {
        int k  = q >> 6;
        int wo = q & 63;
        float dy = off_n[(2 * k) * (HOUT * WOUT) + wo];
        float dx = off_n[(2 * k + 1) * (HOUT * WOUT) + wo];
        int kh = (k * 171) >> 9;                       // k/3 for k<9
        int kw = k - 3 * kh;
        float py = (float)(ho + kh) + dy;
        float px = (float)(wo + kw) + dx;
        float y0f = floorf(py), x0f = floorf(px);
        float fy = py - y0f, fx = px - x0f;
        int y0 = (int)y0f, x0 = (int)x0f;
        int y1 = y0 + 1,   x1 = x0 + 1;
        float vy0 = (y0 >= 0 && y0 < HIN) ? 1.f : 0.f;
        float vy1 = (y1 >= 0 && y1 < HIN) ? 1.f : 0.f;
        float vx0 = (x0 >= 0 && x0 < WIN) ? 1.f : 0.f;
        float vx1 = (x1 >= 0 && x1 < WIN) ? 1.f : 0.f;
        int y0c = min(max(y0, 0), HIN - 1), y1c = min(max(y1, 0), HIN - 1);
        int x0c = min(max(x0, 0), WIN - 1), x1c = min(max(x1, 0), WIN - 1);
        int a00 = (y0c * WIN + x0c) * CIN;             // <2^19
        int sx  = x1c - x0c;                           // 0/1
        int sy  = y1c - y0c;                           // 0/1
        sA[q] = a00 | (sx << 20) | (sy << 21);
        sWf[q * 4 + 0] = (1.f - fy) * (1.f - fx) * vy0 * vx0;
        sWf[q * 4 + 1] = (1.f - fy) * fx         * vy0 * vx1;
        sWf[q * 4 + 2] = fy * (1.f - fx)         * vy1 * vx0;
        sWf[q * 4 + 3] = fy * fx                 * vy1 * vx1;
    }
    __syncthreads();

    f32x4 acc[4];
#pragma unroll
    for (int rt = 0; rt < 4; ++rt) acc[rt] = (f32x4){0.f, 0.f, 0.f, 0.f};

    const int c0  = (lane & 7) * 8;                    // 8 bf16 channels per lane
    const int grp = lane >> 3;                         // 8 (tap,wo) pairs per wave-iter
    const int h   = lane >> 4;

#pragma unroll 1
    for (int kb = 0; kb < 3; ++kb) {
        // B-fragments: wave owns cout-tile ct=wv; 6 contiguous 1KB wave-loads,
        // issued before gather so latency hides under it.
        bf16x8 breg[6];
#pragma unroll
        for (int ks = 0; ks < 6; ++ks)
            breg[ks] = *(const bf16x8*)(wF + (((wv * 18 + kb * 6 + ks) << 6) + lane) * 8);

        // ---- gather: 192 pairs, 8 bf16 channels per lane, 8 pairs per iter ----
#pragma unroll 3
        for (int it = 0; it < 6; ++it) {
            int p  = wv * 48 + it * 8 + grp;
            int q  = kb * 192 + p;
            int av = sA[q];                            // 8-lane broadcast
            float4 wt = *(const float4*)&sWf[q * 4];
            int a00 = (av & 0xFFFFF) + c0;
            int dxs = (av >> 14) & 64;                 // +CIN elems if x-step
            int dys = ((av >> 21) & 1) * (WIN * CIN);
            int4 u00 = *(const int4*)(nh + a00);               // one 128B line per pair
            int4 u01 = *(const int4*)(nh + a00 + dxs);
            int4 u10 = *(const int4*)(nh + a00 + dys);
            int4 u11 = *(const int4*)(nh + a00 + dys + dxs);
            int4 r;
            r.x = blend_pair(u00.x, u01.x, u10.x, u11.x, wt);
            r.y = blend_pair(u00.y, u01.y, u10.y, u11.y, wt);
            r.z = blend_pair(u00.z, u01.z, u10.z, u11.z, wt);
            r.w = blend_pair(u00.w, u01.w, u10.w, u11.w, wt);
            int k3 = p >> 6, wo = p & 63;
            int slot = (k3 * 8 + (lane & 7)) ^ (wo & 7);
            *(int4*)(smS + wo * 384 + (slot << 4)) = r;
        }
        __syncthreads();

        // ---- GEMM: A (all 64 rows) from swizzled LDS, B from regs ----
#pragma unroll
        for (int rt = 0; rt < 4; ++rt) {
            const int row = rt * 16 + (lane & 15);
#pragma unroll
            for (int ks = 0; ks < 6; ++ks) {
                int aslot = (ks * 4 + h) ^ (row & 7);
                bf16x8 af = *(const bf16x8*)(smS + row * 384 + (aslot << 4));
                acc[rt] = __builtin_amdgcn_mfma_f32_16x16x32_bf16(af, breg[ks], acc[rt], 0, 0, 0);
            }
        }
        __syncthreads();                               // smS reused next kb
    }

    // ---- epilogue: transpose through LDS for coalesced stores ----
    float* red = (float*)sm;                           // [64 couts][65] = 16640 B
#pragma unroll
    for (int rt = 0; rt < 4; ++rt)
#pragma unroll
        for (int r = 0; r < 4; ++r)
            red[(16 * wv + (lane & 15)) * 65 + (16 * rt + h * 4 + r)] = acc[rt][r];
    __syncthreads();
    float* op = out + (size_t)(n * COUT) * (HOUT * WOUT) + ho * WOUT + lane;
#pragma unroll
    for (int j = 0; j < 16; ++j) {
        int co = wv * 16 + j;
        op[(size_t)co * (HOUT * WOUT)] = red[co * 65 + lane];
    }
}

// ---------------- fallback (R2 path) if ws too small ----------------
__global__ __launch_bounds__(256) void repack_w_kernel(const float* __restrict__ w,
                                                       float* __restrict__ wT) {
    int i = blockIdx.x * 256 + threadIdx.x;
    if (i >= KK * CIN * COUT) return;
    int co = i & 63; int t = i >> 6;
    int c = t & 63;  int k = t >> 6;
    wT[i] = w[(co * CIN + c) * KK + k];
}

__global__ __launch_bounds__(256) void dconv_kernel(const float* __restrict__ inp,
                                                    const float* __restrict__ off,
                                                    const float* __restrict__ wT,
                                                    float* __restrict__ out) {
    const int tid = threadIdx.x;
    const int wo  = tid & 63;
    const int g   = tid >> 6;
    const int p   = blockIdx.x;
    const int logical = (p & (NXCD - 1)) * (NB * HOUT / NXCD) + (p >> 3);
    const int n   = logical >> 6;
    const int ho  = logical & 63;
    const int cbase = __builtin_amdgcn_readfirstlane(g << 4);
    float acc[COUT];
#pragma unroll
    for (int i = 0; i < COUT; ++i) acc[i] = 0.f;
    const float* inp_n = inp + n * (CIN * HIN * WIN);
    const float* off_p = off + ((n * (2 * KK)) * HOUT + ho) * WOUT + wo;
#pragma unroll 1
    for (int k = 0; k < KK; ++k) {
        float dy = off_p[(2 * k) * (HOUT * WOUT)];
        float dx = off_p[(2 * k + 1) * (HOUT * WOUT)];
        float py = (float)(ho + k / 3) + dy;
        float px = (float)(wo + k % 3) + dx;
        float y0f = floorf(py), x0f = floorf(px);
        float fy = py - y0f, fx = px - x0f;
        int y0 = (int)y0f, x0 = (int)x0f;
        int y1 = y0 + 1,   x1 = x0 + 1;
        float vy0 = (y0 >= 0 && y0 < HIN) ? 1.f : 0.f;
        float vy1 = (y1 >= 0 && y1 < HIN) ? 1.f : 0.f;
        float vx0 = (x0 >= 0 && x0 < WIN) ? 1.f : 0.f;
        float vx1 = (x1 >= 0 && x1 < WIN) ? 1.f : 0.f;
        int y0c = min(max(y0, 0), HIN - 1), y1c = min(max(y1, 0), HIN - 1);
        int x0c = min(max(x0, 0), WIN - 1), x1c = min(max(x1, 0), WIN - 1);
        int o00 = y0c * WIN + x0c, o01 = y0c * WIN + x1c;
        int o10 = y1c * WIN + x0c, o11 = y1c * WIN + x1c;
        float w00 = (1.f - fy) * (1.f - fx) * vy0 * vx0;
        float w01 = (1.f - fy) * fx * vy0 * vx1;
        float w10 = fy * (1.f - fx) * vy1 * vx0;
        float w11 = fy * fx * vy1 * vx1;
        const float* pc   = inp_n + cbase * (HIN * WIN);
        const float* wrow = wT + ((k * CIN + cbase) << 6);
#pragma unroll 4
        for (int c = 0; c < 16; ++c) {
            float v = w00 * pc[o00] + w01 * pc[o01] + w10 * pc[o10] + w11 * pc[o11];
#pragma unroll
            for (int co = 0; co < COUT; ++co) acc[co] = fmaf(v, wrow[co], acc[co]);
            pc += HIN * WIN; wrow += COUT;
        }
    }
    __shared__ float redf[COUT * WOUT];
    for (int i = tid; i < COUT * WOUT; i += 256) redf[i] = 0.f;
    __syncthreads();
#pragma unroll
    for (int co = 0; co < COUT; ++co) atomicAdd(&redf[co * WOUT + wo], acc[co]);
    __syncthreads();
    float* out_p = out + (n * COUT * HOUT + ho) * WOUT;
    for (int i = tid; i < COUT * WOUT; i += 256) {
        int co = i >> 6, w2 = i & 63;
        out_p[co * (HOUT * WOUT) + w2] = redf[i];
    }
}

extern "C" void kernel_launch(void* const* d_in, const int* in_sizes, int n_in,
                              void* d_out, int out_size, void* d_ws, size_t ws_size,
                              hipStream_t stream) {
    const float* inp = (const float*)d_in[0];
    const float* off = (const float*)d_in[1];
    const float* w   = (const float*)d_in[2];
    float* out = (float*)d_out;

    const size_t nhwc_bytes = (size_t)NB * HIN * WIN * CIN * 2;   // bf16: 8,921,088
    const size_t wF_bytes   = (size_t)4 * 18 * 64 * 8 * 2;        // 73,728

    if (ws_size >= nhwc_bytes + wF_bytes) {
        unsigned short* nhwc = (unsigned short*)d_ws;
        unsigned short* wF   = (unsigned short*)((char*)d_ws + nhwc_bytes);
        repack_wF<<<(4 * 18 * 64 * 8 + 255) / 256, 256, 0, stream>>>(w, wF);
        repack_inp_bf<<<NB * HIN, 256, 0, stream>>>(inp, nhwc);
        dconv5<<<NB * HOUT, 256, 0, stream>>>(nhwc, off, wF, out);
    } else {
        float* wT = (float*)d_ws;
        repack_w_kernel<<<(KK * CIN * COUT + 255) / 256, 256, 0, stream>>>(w, wT);
        dconv_kernel<<<NB * HOUT, 256, 0, stream>>>(inp, off, wT, out);
    }
}

// Round 7
// 37.551 us; speedup vs baseline: 1.9646x; 1.1130x over previous
//
#include <hip/hip_runtime.h>
#include <hip/hip_bf16.h>

#define NB    16
#define CIN   64
#define COUT  64
#define HIN   66
#define WIN   66
#define HOUT  64
#define WOUT  64
#define KK    9
#define NXCD  8

typedef __attribute__((ext_vector_type(8))) short bf16x8;
typedef __attribute__((ext_vector_type(4))) float f32x4;

static __device__ __forceinline__ unsigned int f2bf_u(float f) {
    union { float f; unsigned int u; } x; x.f = f;
    return (x.u + 0x7fff + ((x.u >> 16) & 1)) >> 16;      // RNE
}

static __device__ __forceinline__ unsigned int blend_pair(unsigned int d00, unsigned int d01,
                                                          unsigned int d10, unsigned int d11,
                                                          float4 wt) {
    float lo = wt.x * __uint_as_float(d00 << 16) + wt.y * __uint_as_float(d01 << 16)
             + wt.z * __uint_as_float(d10 << 16) + wt.w * __uint_as_float(d11 << 16);
    float hi = wt.x * __uint_as_float(d00 & 0xFFFF0000u) + wt.y * __uint_as_float(d01 & 0xFFFF0000u)
             + wt.z * __uint_as_float(d10 & 0xFFFF0000u) + wt.w * __uint_as_float(d11 & 0xFFFF0000u);
    return f2bf_u(lo) | (f2bf_u(hi) << 16);
}

// ---------------- merged repack: NCHW f32 -> NHWC bf16  +  W -> fragment-major bf16 ----------------
// blocks [0, NB*HIN)           : input transpose rows
// blocks [NB*HIN, NB*HIN+144)  : weight fragments (4*18*64*8 = 36864 elems)
__global__ __launch_bounds__(256) void repack_all(const float* __restrict__ in,
                                                  const float* __restrict__ w,
                                                  unsigned short* __restrict__ nhwc,
                                                  unsigned short* __restrict__ wF) {
    int b = blockIdx.x;
    if (b < NB * HIN) {
        int n = b / HIN, y = b % HIN;
        __shared__ float buf[CIN * 67];
        const float* src = in + (size_t)(n * CIN) * HIN * WIN + y * WIN;
        for (int i = threadIdx.x; i < CIN * WIN; i += 256) {
            int c = i / WIN, x = i - c * WIN;
            buf[c * 67 + x] = src[c * (HIN * WIN) + x];
        }
        __syncthreads();
        unsigned short* dst = nhwc + (size_t)((n * HIN + y) * WIN) * CIN;
        for (int i = threadIdx.x; i < CIN * WIN; i += 256) {
            int x = i >> 6, c = i & 63;
            dst[x * CIN + c] = (unsigned short)f2bf_u(buf[c * 67 + x]);
        }
    } else {
        int i = (b - NB * HIN) * 256 + threadIdx.x;
        if (i >= 4 * 18 * 64 * 8) return;
        int j    = i & 7;
        int t    = i >> 3;
        int lane = t & 63;  t >>= 6;
        int ksg  = t % 18;
        int ct   = t / 18;
        int kb = ksg / 6, ks = ksg % 6;
        int klocal = ks * 32 + (lane >> 4) * 8 + j;
        int tap = kb * 3 + (klocal >> 6);
        int cin = klocal & 63;
        int cout = ct * 16 + (lane & 15);
        wF[i] = (unsigned short)f2bf_u(w[(cout * CIN + cin) * KK + tap]);
    }
}

// ---------------- main: implicit-GEMM deformable conv via MFMA ----------------
__global__ __launch_bounds__(256, 4) void dconv6(const unsigned short* __restrict__ nhwc,
                                                 const float* __restrict__ off,
                                                 const unsigned short* __restrict__ wF,
                                                 float* __restrict__ out) {
    __shared__ __align__(16) char sm[36096];
    char*  smS = sm;                                   // 24576: sampled tile (swizzled)
    int*   sA  = (int*)(sm + 24576);                   // 576 packed addrs
    float* sWf = (float*)(sm + 26880);                 // 576*4 bilinear weights

    const int tid  = threadIdx.x;
    const int lane = tid & 63;
    const int wv   = tid >> 6;
    const int p0 = blockIdx.x;
    const int logical = (p0 & (NXCD - 1)) * (NB * HOUT / NXCD) + (p0 >> 3);
    const int n  = logical >> 6;
    const int ho = logical & 63;

    const unsigned short* nh = nhwc + (size_t)n * (HIN * WIN * CIN);
    const float* off_n = off + (size_t)n * (2 * KK * HOUT * WOUT) + ho * WOUT;

    // ---- S1: bilinear meta per (tap,wo): packed addr/steps + 4 f32 weights ----
    for (int q = tid; q < KK * 64; q += 256) {
        int k  = q >> 6;
        int wo = q & 63;
        float dy = off_n[(2 * k) * (HOUT * WOUT) + wo];
        float dx = off_n[(2 * k + 1) * (HOUT * WOUT) + wo];
        int kh = (k * 171) >> 9;                       // k/3 for k<9
        int kw = k - 3 * kh;
        float py = (float)(ho + kh) + dy;
        float px = (float)(wo + kw) + dx;
        float y0f = floorf(py), x0f = floorf(px);
        float fy = py - y0f, fx = px - x0f;
        int y0 = (int)y0f, x0 = (int)x0f;
        int y1 = y0 + 1,   x1 = x0 + 1;
        float vy0 = (y0 >= 0 && y0 < HIN) ? 1.f : 0.f;
        float vy1 = (y1 >= 0 && y1 < HIN) ? 1.f : 0.f;
        float vx0 = (x0 >= 0 && x0 < WIN) ? 1.f : 0.f;
        float vx1 = (x1 >= 0 && x1 < WIN) ? 1.f : 0.f;
        int y0c = min(max(y0, 0), HIN - 1), y1c = min(max(y1, 0), HIN - 1);
        int x0c = min(max(x0, 0), WIN - 1), x1c = min(max(x1, 0), WIN - 1);
        int a00 = (y0c * WIN + x0c) * CIN;             // <2^19
        int sx  = x1c - x0c;                           // 0/1
        int sy  = y1c - y0c;                           // 0/1
        sA[q] = a00 | (sx << 20) | (sy << 21);
        sWf[q * 4 + 0] = (1.f - fy) * (1.f - fx) * vy0 * vx0;
        sWf[q * 4 + 1] = (1.f - fy) * fx         * vy0 * vx1;
        sWf[q * 4 + 2] = fy * (1.f - fx)         * vy1 * vx0;
        sWf[q * 4 + 3] = fy * fx                 * vy1 * vx1;
    }
    __syncthreads();

    f32x4 acc[4];
#pragma unroll
    for (int rt = 0; rt < 4; ++rt) acc[rt] = (f32x4){0.f, 0.f, 0.f, 0.f};

    const int c0  = (lane & 7) * 8;                    // 8 bf16 channels per lane
    const int grp = lane >> 3;                         // 8 (tap,wo) pairs per wave-iter
    const int h   = lane >> 4;

#pragma unroll 1
    for (int kb = 0; kb < 3; ++kb) {
        // B-fragments: wave owns cout-tile ct=wv; 6 contiguous 1KB wave-loads.
        bf16x8 breg[6];
#pragma unroll
        for (int ks = 0; ks < 6; ++ks)
            breg[ks] = *(const bf16x8*)(wF + (((wv * 18 + kb * 6 + ks) << 6) + lane) * 8);

        // ---- gather: 48 pairs/wave, batched 2 pairs (8 loads) in flight ----
#pragma unroll 1
        for (int half = 0; half < 3; ++half) {
            int pA = wv * 48 + (half * 2) * 8 + grp;
            int pB = pA + 8;
            int qA = kb * 192 + pA,  qB = kb * 192 + pB;
            int avA = sA[qA],        avB = sA[qB];
            float4 wtA = *(const float4*)&sWf[qA * 4];
            float4 wtB = *(const float4*)&sWf[qB * 4];
            int aA  = (avA & 0xFFFFF) + c0,           aB  = (avB & 0xFFFFF) + c0;
            int dxA = (avA >> 14) & 64,               dxB = (avB >> 14) & 64;
            int dyA = ((avA >> 21) & 1) * (WIN*CIN),  dyB = ((avB >> 21) & 1) * (WIN*CIN);
            int4 uA0 = *(const int4*)(nh + aA);
            int4 uA1 = *(const int4*)(nh + aA + dxA);
            int4 uA2 = *(const int4*)(nh + aA + dyA);
            int4 uA3 = *(const int4*)(nh + aA + dyA + dxA);
            int4 uB0 = *(const int4*)(nh + aB);
            int4 uB1 = *(const int4*)(nh + aB + dxB);
            int4 uB2 = *(const int4*)(nh + aB + dyB);
            int4 uB3 = *(const int4*)(nh + aB + dyB + dxB);
            int4 rA, rB;
            rA.x = blend_pair(uA0.x, uA1.x, uA2.x, uA3.x, wtA);
            rA.y = blend_pair(uA0.y, uA1.y, uA2.y, uA3.y, wtA);
            rA.z = blend_pair(uA0.z, uA1.z, uA2.z, uA3.z, wtA);
            rA.w = blend_pair(uA0.w, uA1.w, uA2.w, uA3.w, wtA);
            rB.x = blend_pair(uB0.x, uB1.x, uB2.x, uB3.x, wtB);
            rB.y = blend_pair(uB0.y, uB1.y, uB2.y, uB3.y, wtB);
            rB.z = blend_pair(uB0.z, uB1.z, uB2.z, uB3.z, wtB);
            rB.w = blend_pair(uB0.w, uB1.w, uB2.w, uB3.w, wtB);
            int k3A = pA >> 6, woA = pA & 63;
            int k3B = pB >> 6, woB = pB & 63;
            int slA = (k3A * 8 + (lane & 7)) ^ (woA & 7);
            int slB = (k3B * 8 + (lane & 7)) ^ (woB & 7);
            *(int4*)(smS + woA * 384 + (slA << 4)) = rA;
            *(int4*)(smS + woB * 384 + (slB << 4)) = rB;
        }
        __syncthreads();

        // ---- GEMM: A (all 64 rows) from swizzled LDS, B from regs ----
#pragma unroll
        for (int rt = 0; rt < 4; ++rt) {
            const int row = rt * 16 + (lane & 15);
#pragma unroll
            for (int ks = 0; ks < 6; ++ks) {
                int aslot = (ks * 4 + h) ^ (row & 7);
                bf16x8 af = *(const bf16x8*)(smS + row * 384 + (aslot << 4));
                acc[rt] = __builtin_amdgcn_mfma_f32_16x16x32_bf16(af, breg[ks], acc[rt], 0, 0, 0);
            }
        }
        __syncthreads();                               // smS reused next kb
    }

    // ---- epilogue: transpose through LDS for coalesced stores ----
    float* red = (float*)sm;                           // [64 couts][65] = 16640 B
#pragma unroll
    for (int rt = 0; rt < 4; ++rt)
#pragma unroll
        for (int r = 0; r < 4; ++r)
            red[(16 * wv + (lane & 15)) * 65 + (16 * rt + h * 4 + r)] = acc[rt][r];
    __syncthreads();
    float* op = out + (size_t)(n * COUT) * (HOUT * WOUT) + ho * WOUT + lane;
#pragma unroll
    for (int j = 0; j < 16; ++j) {
        int co = wv * 16 + j;
        op[(size_t)co * (HOUT * WOUT)] = red[co * 65 + lane];
    }
}

// ---------------- fallback (R2 path) if ws too small ----------------
__global__ __launch_bounds__(256) void repack_w_kernel(const float* __restrict__ w,
                                                       float* __restrict__ wT) {
    int i = blockIdx.x * 256 + threadIdx.x;
    if (i >= KK * CIN * COUT) return;
    int co = i & 63; int t = i >> 6;
    int c = t & 63;  int k = t >> 6;
    wT[i] = w[(co * CIN + c) * KK + k];
}

__global__ __launch_bounds__(256) void dconv_kernel(const float* __restrict__ inp,
                                                    const float* __restrict__ off,
                                                    const float* __restrict__ wT,
                                                    float* __restrict__ out) {
    const int tid = threadIdx.x;
    const int wo  = tid & 63;
    const int g   = tid >> 6;
    const int p   = blockIdx.x;
    const int logical = (p & (NXCD - 1)) * (NB * HOUT / NXCD) + (p >> 3);
    const int n   = logical >> 6;
    const int ho  = logical & 63;
    const int cbase = __builtin_amdgcn_readfirstlane(g << 4);
    float acc[COUT];
#pragma unroll
    for (int i = 0; i < COUT; ++i) acc[i] = 0.f;
    const float* inp_n = inp + n * (CIN * HIN * WIN);
    const float* off_p = off + ((n * (2 * KK)) * HOUT + ho) * WOUT + wo;
#pragma unroll 1
    for (int k = 0; k < KK; ++k) {
        float dy = off_p[(2 * k) * (HOUT * WOUT)];
        float dx = off_p[(2 * k + 1) * (HOUT * WOUT)];
        float py = (float)(ho + k / 3) + dy;
        float px = (float)(wo + k % 3) + dx;
        float y0f = floorf(py), x0f = floorf(px);
        float fy = py - y0f, fx = px - x0f;
        int y0 = (int)y0f, x0 = (int)x0f;
        int y1 = y0 + 1,   x1 = x0 + 1;
        float vy0 = (y0 >= 0 && y0 < HIN) ? 1.f : 0.f;
        float vy1 = (y1 >= 0 && y1 < HIN) ? 1.f : 0.f;
        float vx0 = (x0 >= 0 && x0 < WIN) ? 1.f : 0.f;
        float vx1 = (x1 >= 0 && x1 < WIN) ? 1.f : 0.f;
        int y0c = min(max(y0, 0), HIN - 1), y1c = min(max(y1, 0), HIN - 1);
        int x0c = min(max(x0, 0), WIN - 1), x1c = min(max(x1, 0), WIN - 1);
        int o00 = y0c * WIN + x0c, o01 = y0c * WIN + x1c;
        int o10 = y1c * WIN + x0c, o11 = y1c * WIN + x1c;
        float w00 = (1.f - fy) * (1.f - fx) * vy0 * vx0;
        float w01 = (1.f - fy) * fx * vy0 * vx1;
        float w10 = fy * (1.f - fx) * vy1 * vx0;
        float w11 = fy * fx * vy1 * vx1;
        const float* pc   = inp_n + cbase * (HIN * WIN);
        const float* wrow = wT + ((k * CIN + cbase) << 6);
#pragma unroll 4
        for (int c = 0; c < 16; ++c) {
            float v = w00 * pc[o00] + w01 * pc[o01] + w10 * pc[o10] + w11 * pc[o11];
#pragma unroll
            for (int co = 0; co < COUT; ++co) acc[co] = fmaf(v, wrow[co], acc[co]);
            pc += HIN * WIN; wrow += COUT;
        }
    }
    __shared__ float redf[COUT * WOUT];
    for (int i = tid; i < COUT * WOUT; i += 256) redf[i] = 0.f;
    __syncthreads();
#pragma unroll
    for (int co = 0; co < COUT; ++co) atomicAdd(&redf[co * WOUT + wo], acc[co]);
    __syncthreads();
    float* out_p = out + (n * COUT * HOUT + ho) * WOUT;
    for (int i = tid; i < COUT * WOUT; i += 256) {
        int co = i >> 6, w2 = i & 63;
        out_p[co * (HOUT * WOUT) + w2] = redf[i];
    }
}

extern "C" void kernel_launch(void* const* d_in, const int* in_sizes, int n_in,
                              void* d_out, int out_size, void* d_ws, size_t ws_size,
                              hipStream_t stream) {
    const float* inp = (const float*)d_in[0];
    const float* off = (const float*)d_in[1];
    const float* w   = (const float*)d_in[2];
    float* out = (float*)d_out;

    const size_t nhwc_bytes = (size_t)NB * HIN * WIN * CIN * 2;   // bf16: 8,921,088
    const size_t wF_bytes   = (size_t)4 * 18 * 64 * 8 * 2;        // 73,728

    if (ws_size >= nhwc_bytes + wF_bytes) {
        unsigned short* nhwc = (unsigned short*)d_ws;
        unsigned short* wF   = (unsigned short*)((char*)d_ws + nhwc_bytes);
        repack_all<<<NB * HIN + 144, 256, 0, stream>>>(inp, w, nhwc, wF);
        dconv6<<<NB * HOUT, 256, 0, stream>>>(nhwc, off, wF, out);
    } else {
        float* wT = (float*)d_ws;
        repack_w_kernel<<<(KK * CIN * COUT + 255) / 256, 256, 0, stream>>>(w, wT);
        dconv_kernel<<<NB * HOUT, 256, 0, stream>>>(inp, off, wT, out);
    }
}

// Round 8
// 35.551 us; speedup vs baseline: 2.0751x; 1.0562x over previous
//
#include <hip/hip_runtime.h>
#include <hip/hip_bf16.h>

#define NB    16
#define CIN   64
#define COUT  64
#define HIN   66
#define WIN   66
#define HOUT  64
#define WOUT  64
#define KK    9
#define NXCD  8

typedef __attribute__((ext_vector_type(8))) short bf16x8;
typedef __attribute__((ext_vector_type(4))) float f32x4;

static __device__ __forceinline__ unsigned int f2bf_u(float f) {
    union { float f; unsigned int u; } x; x.f = f;
    return (x.u + 0x7fff + ((x.u >> 16) & 1)) >> 16;      // RNE
}

static __device__ __forceinline__ unsigned int blend_pair(unsigned int d00, unsigned int d01,
                                                          unsigned int d10, unsigned int d11,
                                                          float4 wt) {
    float lo = wt.x * __uint_as_float(d00 << 16) + wt.y * __uint_as_float(d01 << 16)
             + wt.z * __uint_as_float(d10 << 16) + wt.w * __uint_as_float(d11 << 16);
    float hi = wt.x * __uint_as_float(d00 & 0xFFFF0000u) + wt.y * __uint_as_float(d01 & 0xFFFF0000u)
             + wt.z * __uint_as_float(d10 & 0xFFFF0000u) + wt.w * __uint_as_float(d11 & 0xFFFF0000u);
    return f2bf_u(lo) | (f2bf_u(hi) << 16);
}

// ---------------- merged repack: NCHW f32 -> NHWC bf16  +  W -> fragment-major bf16 ----------------
__global__ __launch_bounds__(256) void repack_all(const float* __restrict__ in,
                                                  const float* __restrict__ w,
                                                  unsigned short* __restrict__ nhwc,
                                                  unsigned short* __restrict__ wF) {
    int b = blockIdx.x;
    if (b < NB * HIN) {
        int n = b / HIN, y = b % HIN;
        __shared__ float buf[CIN * 67];
        const float* src = in + (size_t)(n * CIN) * HIN * WIN + y * WIN;
        for (int i = threadIdx.x; i < CIN * WIN; i += 256) {
            int c = i / WIN, x = i - c * WIN;
            buf[c * 67 + x] = src[c * (HIN * WIN) + x];
        }
        __syncthreads();
        unsigned short* dst = nhwc + (size_t)((n * HIN + y) * WIN) * CIN;
        for (int i = threadIdx.x; i < CIN * WIN; i += 256) {
            int x = i >> 6, c = i & 63;
            dst[x * CIN + c] = (unsigned short)f2bf_u(buf[c * 67 + x]);
        }
    } else {
        int i = (b - NB * HIN) * 256 + threadIdx.x;
        if (i >= 4 * 18 * 64 * 8) return;
        int j    = i & 7;
        int t    = i >> 3;
        int lane = t & 63;  t >>= 6;
        int ksg  = t % 18;
        int ct   = t / 18;
        int kb = ksg / 6, ks = ksg % 6;
        int klocal = ks * 32 + (lane >> 4) * 8 + j;
        int tap = kb * 3 + (klocal >> 6);
        int cin = klocal & 63;
        int cout = ct * 16 + (lane & 15);
        wF[i] = (unsigned short)f2bf_u(w[(cout * CIN + cin) * KK + tap]);
    }
}

struct GB { int4 u0, u1, u2, u3; float4 wt; int p; };

// ---------------- main: implicit-GEMM deformable conv via MFMA ----------------
__global__ __launch_bounds__(256, 4) void dconv7(const unsigned short* __restrict__ nhwc,
                                                 const float* __restrict__ off,
                                                 const unsigned short* __restrict__ wF,
                                                 float* __restrict__ out) {
    __shared__ __align__(16) char sm[36096];
    char*  smS = sm;                                   // 24576: sampled tile (swizzled)
    int*   sA  = (int*)(sm + 24576);                   // 576 packed addrs
    float* sWf = (float*)(sm + 26880);                 // 576*4 bilinear weights

    const int tid  = threadIdx.x;
    const int lane = tid & 63;
    const int wv   = tid >> 6;
    const int p0 = blockIdx.x;
    const int logical = (p0 & (NXCD - 1)) * (NB * HOUT / NXCD) + (p0 >> 3);
    const int n  = logical >> 6;
    const int ho = logical & 63;

    const unsigned short* nh = nhwc + (size_t)n * (HIN * WIN * CIN);
    const float* off_n = off + (size_t)n * (2 * KK * HOUT * WOUT) + ho * WOUT;

    // ---- S1: bilinear meta per (tap,wo): packed addr/steps + 4 f32 weights ----
    for (int q = tid; q < KK * 64; q += 256) {
        int k  = q >> 6;
        int wo = q & 63;
        float dy = off_n[(2 * k) * (HOUT * WOUT) + wo];
        float dx = off_n[(2 * k + 1) * (HOUT * WOUT) + wo];
        int kh = (k * 171) >> 9;                       // k/3 for k<9
        int kw = k - 3 * kh;
        float py = (float)(ho + kh) + dy;
        float px = (float)(wo + kw) + dx;
        float y0f = floorf(py), x0f = floorf(px);
        float fy = py - y0f, fx = px - x0f;
        int y0 = (int)y0f, x0 = (int)x0f;
        int y1 = y0 + 1,   x1 = x0 + 1;
        float vy0 = (y0 >= 0 && y0 < HIN) ? 1.f : 0.f;
        float vy1 = (y1 >= 0 && y1 < HIN) ? 1.f : 0.f;
        float vx0 = (x0 >= 0 && x0 < WIN) ? 1.f : 0.f;
        float vx1 = (x1 >= 0 && x1 < WIN) ? 1.f : 0.f;
        int y0c = min(max(y0, 0), HIN - 1), y1c = min(max(y1, 0), HIN - 1);
        int x0c = min(max(x0, 0), WIN - 1), x1c = min(max(x1, 0), WIN - 1);
        int a00 = (y0c * WIN + x0c) * CIN;             // <2^19
        int sx  = x1c - x0c;                           // 0/1
        int sy  = y1c - y0c;                           // 0/1
        sA[q] = a00 | (sx << 20) | (sy << 21);
        sWf[q * 4 + 0] = (1.f - fy) * (1.f - fx) * vy0 * vx0;
        sWf[q * 4 + 1] = (1.f - fy) * fx         * vy0 * vx1;
        sWf[q * 4 + 2] = fy * (1.f - fx)         * vy1 * vx0;
        sWf[q * 4 + 3] = fy * fx                 * vy1 * vx1;
    }
    __syncthreads();

    f32x4 acc[4];
#pragma unroll
    for (int rt = 0; rt < 4; ++rt) acc[rt] = (f32x4){0.f, 0.f, 0.f, 0.f};

    const int c0  = (lane & 7) * 8;                    // 8 bf16 channels per lane
    const int grp = lane >> 3;                         // pair-slot within batch of 8
    const int h   = lane >> 4;

    // pair index J=0..5: p = wv*48 + (J>>1)*16 + (J&1)*8 + grp
#define LOADP(G, KB, J) do {                                           \
        int p_ = wv * 48 + ((J) >> 1) * 16 + ((J) & 1) * 8 + grp;      \
        int q_ = (KB) * 192 + p_;                                      \
        int av_ = sA[q_];                                              \
        G.wt = *(const float4*)&sWf[q_ * 4];                           \
        int a_  = (av_ & 0xFFFFF) + c0;                                \
        int dx_ = (av_ >> 14) & 64;                                    \
        int dy_ = ((av_ >> 21) & 1) * (WIN * CIN);                     \
        G.u0 = *(const int4*)(nh + a_);                                \
        G.u1 = *(const int4*)(nh + a_ + dx_);                          \
        G.u2 = *(const int4*)(nh + a_ + dy_);                          \
        G.u3 = *(const int4*)(nh + a_ + dy_ + dx_);                    \
        G.p = p_;                                                      \
    } while (0)

#define PROCP(G) do {                                                  \
        int4 r_;                                                       \
        r_.x = blend_pair(G.u0.x, G.u1.x, G.u2.x, G.u3.x, G.wt);       \
        r_.y = blend_pair(G.u0.y, G.u1.y, G.u2.y, G.u3.y, G.wt);       \
        r_.z = blend_pair(G.u0.z, G.u1.z, G.u2.z, G.u3.z, G.wt);       \
        r_.w = blend_pair(G.u0.w, G.u1.w, G.u2.w, G.u3.w, G.wt);       \
        int k3_ = G.p >> 6, wo_ = G.p & 63;                            \
        int sl_ = (k3_ * 8 + (lane & 7)) ^ (wo_ & 7);                  \
        *(int4*)(smS + wo_ * 384 + (sl_ << 4)) = r_;                   \
    } while (0)

    GB a0, a1;
    LOADP(a0, 0, 0);                                   // prologue: first pair in flight

#pragma unroll
    for (int kb = 0; kb < 3; ++kb) {
        // B-fragments for this kb: 6 contiguous 1KB wave-loads, in flight during gather
        bf16x8 breg[6];
#pragma unroll
        for (int ks = 0; ks < 6; ++ks)
            breg[ks] = *(const bf16x8*)(wF + (((wv * 18 + kb * 6 + ks) << 6) + lane) * 8);

        // ---- pipelined gather: load pair j+1 while blending pair j ----
        LOADP(a1, kb, 1); PROCP(a0);
        LOADP(a0, kb, 2); PROCP(a1);
        LOADP(a1, kb, 3); PROCP(a0);
        LOADP(a0, kb, 4); PROCP(a1);
        LOADP(a1, kb, 5); PROCP(a0);
        PROCP(a1);
        __syncthreads();

        if (kb < 2) LOADP(a0, kb + 1, 0);              // next kb's first pair rides under GEMM

        // ---- GEMM: A (all 64 rows) from swizzled LDS, B from regs ----
#pragma unroll
        for (int rt = 0; rt < 4; ++rt) {
            const int row = rt * 16 + (lane & 15);
#pragma unroll
            for (int ks = 0; ks < 6; ++ks) {
                int aslot = (ks * 4 + h) ^ (row & 7);
                bf16x8 af = *(const bf16x8*)(smS + row * 384 + (aslot << 4));
                acc[rt] = __builtin_amdgcn_mfma_f32_16x16x32_bf16(af, breg[ks], acc[rt], 0, 0, 0);
            }
        }
        __syncthreads();                               // smS reused next kb
    }
#undef LOADP
#undef PROCP

    // ---- epilogue: transpose through LDS for coalesced stores ----
    float* red = (float*)sm;                           // [64 couts][65] = 16640 B
#pragma unroll
    for (int rt = 0; rt < 4; ++rt)
#pragma unroll
        for (int r = 0; r < 4; ++r)
            red[(16 * wv + (lane & 15)) * 65 + (16 * rt + h * 4 + r)] = acc[rt][r];
    __syncthreads();
    float* op = out + (size_t)(n * COUT) * (HOUT * WOUT) + ho * WOUT + lane;
#pragma unroll
    for (int j = 0; j < 16; ++j) {
        int co = wv * 16 + j;
        op[(size_t)co * (HOUT * WOUT)] = red[co * 65 + lane];
    }
}

// ---------------- fallback (R2 path) if ws too small ----------------
__global__ __launch_bounds__(256) void repack_w_kernel(const float* __restrict__ w,
                                                       float* __restrict__ wT) {
    int i = blockIdx.x * 256 + threadIdx.x;
    if (i >= KK * CIN * COUT) return;
    int co = i & 63; int t = i >> 6;
    int c = t & 63;  int k = t >> 6;
    wT[i] = w[(co * CIN + c) * KK + k];
}

__global__ __launch_bounds__(256) void dconv_kernel(const float* __restrict__ inp,
                                                    const float* __restrict__ off,
                                                    const float* __restrict__ wT,
                                                    float* __restrict__ out) {
    const int tid = threadIdx.x;
    const int wo  = tid & 63;
    const int g   = tid >> 6;
    const int p   = blockIdx.x;
    const int logical = (p & (NXCD - 1)) * (NB * HOUT / NXCD) + (p >> 3);
    const int n   = logical >> 6;
    const int ho  = logical & 63;
    const int cbase = __builtin_amdgcn_readfirstlane(g << 4);
    float acc[COUT];
#pragma unroll
    for (int i = 0; i < COUT; ++i) acc[i] = 0.f;
    const float* inp_n = inp + n * (CIN * HIN * WIN);
    const float* off_p = off + ((n * (2 * KK)) * HOUT + ho) * WOUT + wo;
#pragma unroll 1
    for (int k = 0; k < KK; ++k) {
        float dy = off_p[(2 * k) * (HOUT * WOUT)];
        float dx = off_p[(2 * k + 1) * (HOUT * WOUT)];
        float py = (float)(ho + k / 3) + dy;
        float px = (float)(wo + k % 3) + dx;
        float y0f = floorf(py), x0f = floorf(px);
        float fy = py - y0f, fx = px - x0f;
        int y0 = (int)y0f, x0 = (int)x0f;
        int y1 = y0 + 1,   x1 = x0 + 1;
        float vy0 = (y0 >= 0 && y0 < HIN) ? 1.f : 0.f;
        float vy1 = (y1 >= 0 && y1 < HIN) ? 1.f : 0.f;
        float vx0 = (x0 >= 0 && x0 < WIN) ? 1.f : 0.f;
        float vx1 = (x1 >= 0 && x1 < WIN) ? 1.f : 0.f;
        int y0c = min(max(y0, 0), HIN - 1), y1c = min(max(y1, 0), HIN - 1);
        int x0c = min(max(x0, 0), WIN - 1), x1c = min(max(x1, 0), WIN - 1);
        int o00 = y0c * WIN + x0c, o01 = y0c * WIN + x1c;
        int o10 = y1c * WIN + x0c, o11 = y1c * WIN + x1c;
        float w00 = (1.f - fy) * (1.f - fx) * vy0 * vx0;
        float w01 = (1.f - fy) * fx * vy0 * vx1;
        float w10 = fy * (1.f - fx) * vy1 * vx0;
        float w11 = fy * fx * vy1 * vx1;
        const float* pc   = inp_n + cbase * (HIN * WIN);
        const float* wrow = wT + ((k * CIN + cbase) << 6);
#pragma unroll 4
        for (int c = 0; c < 16; ++c) {
            float v = w00 * pc[o00] + w01 * pc[o01] + w10 * pc[o10] + w11 * pc[o11];
#pragma unroll
            for (int co = 0; co < COUT; ++co) acc[co] = fmaf(v, wrow[co], acc[co]);
            pc += HIN * WIN; wrow += COUT;
        }
    }
    __shared__ float redf[COUT * WOUT];
    for (int i = tid; i < COUT * WOUT; i += 256) redf[i] = 0.f;
    __syncthreads();
#pragma unroll
    for (int co = 0; co < COUT; ++co) atomicAdd(&redf[co * WOUT + wo], acc[co]);
    __syncthreads();
    float* out_p = out + (n * COUT * HOUT + ho) * WOUT;
    for (int i = tid; i < COUT * WOUT; i += 256) {
        int co = i >> 6, w2 = i & 63;
        out_p[co * (HOUT * WOUT) + w2] = redf[i];
    }
}

extern "C" void kernel_launch(void* const* d_in, const int* in_sizes, int n_in,
                              void* d_out, int out_size, void* d_ws, size_t ws_size,
                              hipStream_t stream) {
    const float* inp = (const float*)d_in[0];
    const float* off = (const float*)d_in[1];
    const float* w   = (const float*)d_in[2];
    float* out = (float*)d_out;

    const size_t nhwc_bytes = (size_t)NB * HIN * WIN * CIN * 2;   // bf16: 8,921,088
    const size_t wF_bytes   = (size_t)4 * 18 * 64 * 8 * 2;        // 73,728

    if (ws_size >= nhwc_bytes + wF_bytes) {
        unsigned short* nhwc = (unsigned short*)d_ws;
        unsigned short* wF   = (unsigned short*)((char*)d_ws + nhwc_bytes);
        repack_all<<<NB * HIN + 144, 256, 0, stream>>>(inp, w, nhwc, wF);
        dconv7<<<NB * HOUT, 256, 0, stream>>>(nhwc, off, wF, out);
    } else {
        float* wT = (float*)d_ws;
        repack_w_kernel<<<(KK * CIN * COUT + 255) / 256, 256, 0, stream>>>(w, wT);
        dconv_kernel<<<NB * HOUT, 256, 0, stream>>>(inp, off, wT, out);
    }
}

// Round 9
// 34.402 us; speedup vs baseline: 2.1445x; 1.0334x over previous
//
#include <hip/hip_runtime.h>
#include <hip/hip_bf16.h>

#define NB    16
#define CIN   64
#define COUT  64
#define HIN   66
#define WIN   66
#define HOUT  64
#define WOUT  64
#define KK    9
#define NXCD  8

typedef __attribute__((ext_vector_type(8))) short bf16x8;
typedef __attribute__((ext_vector_type(4))) float f32x4;
typedef __attribute__((ext_vector_type(2))) float f32x2;

static __device__ __forceinline__ unsigned int pkbf(float lo, float hi) {
    union { __hip_bfloat162 b; unsigned int u; } x;
    x.b = __float22bfloat162_rn(make_float2(lo, hi));   // v_cvt_pk_bf16_f32
    return x.u;
}

static __device__ __forceinline__ f32x2 up2(unsigned int w) {
    f32x2 r;
    r.x = __uint_as_float(w << 16);
    r.y = __uint_as_float(w & 0xFFFF0000u);
    return r;
}

static __device__ __forceinline__ unsigned int blend_word(unsigned int d00, unsigned int d01,
                                                          unsigned int d10, unsigned int d11,
                                                          f32x2 W00, f32x2 W01, f32x2 W10, f32x2 W11) {
    f32x2 v = W00 * up2(d00);           // v_pk_mul/_fma_f32
    v += W01 * up2(d01);
    v += W10 * up2(d10);
    v += W11 * up2(d11);
    return pkbf(v.x, v.y);
}

// ---------------- merged repack: NCHW f32 -> NHWC bf16  +  W -> fragment-major bf16 ----------------
__global__ __launch_bounds__(256) void repack_all(const float* __restrict__ in,
                                                  const float* __restrict__ w,
                                                  unsigned short* __restrict__ nhwc,
                                                  unsigned short* __restrict__ wF) {
    int b = blockIdx.x;
    if (b < NB * HIN) {
        int n = b / HIN, y = b % HIN;
        __shared__ float buf[CIN * 67];
        const float* src = in + (size_t)(n * CIN) * HIN * WIN + y * WIN;
        for (int i = threadIdx.x; i < CIN * WIN; i += 256) {
            int c = i / WIN, x = i - c * WIN;
            buf[c * 67 + x] = src[c * (HIN * WIN) + x];
        }
        __syncthreads();
        unsigned int* dst = (unsigned int*)(nhwc + (size_t)((n * HIN + y) * WIN) * CIN);
        for (int i = threadIdx.x; i < WIN * (CIN / 2); i += 256) {
            int x = i >> 5, c2 = (i & 31) * 2;          // pair of channels
            dst[x * 32 + (c2 >> 1)] = pkbf(buf[c2 * 67 + x], buf[(c2 + 1) * 67 + x]);
        }
    } else {
        int i = (b - NB * HIN) * 256 + threadIdx.x;
        if (i >= 4 * 18 * 64 * 8) return;
        int j    = i & 7;
        int t    = i >> 3;
        int lane = t & 63;  t >>= 6;
        int ksg  = t % 18;
        int ct   = t / 18;
        int kb = ksg / 6, ks = ksg % 6;
        int klocal = ks * 32 + (lane >> 4) * 8 + j;
        int tap = kb * 3 + (klocal >> 6);
        int cin = klocal & 63;
        int cout = ct * 16 + (lane & 15);
        wF[i] = (unsigned short)(pkbf(w[(cout * CIN + cin) * KK + tap], 0.f) & 0xFFFF);
    }
}

struct GB { int4 u0, u1, u2, u3; int2 aw; int p; };

// ---------------- main: implicit-GEMM deformable conv via MFMA ----------------
__global__ __launch_bounds__(256, 4) void dconv8(const unsigned short* __restrict__ nhwc,
                                                 const float* __restrict__ off,
                                                 const unsigned short* __restrict__ wF,
                                                 float* __restrict__ out) {
    __shared__ __align__(16) char sm[31488];
    char* smS = sm;                                    // 24576: sampled tile (swizzled)
    int*  sAv = (int*)(sm + 24576);                    // 576 packed addrs      (2304 B)
    int2* sAw = (int2*)(sm + 26880);                   // 576 bf16x4 bilinear wts (4608 B)

    const int tid  = threadIdx.x;
    const int lane = tid & 63;
    const int wv   = tid >> 6;
    const int p0 = blockIdx.x;
    const int logical = (p0 & (NXCD - 1)) * (NB * HOUT / NXCD) + (p0 >> 3);
    const int n  = logical >> 6;
    const int ho = logical & 63;

    const unsigned short* nh = nhwc + (size_t)n * (HIN * WIN * CIN);
    const float* off_n = off + (size_t)n * (2 * KK * HOUT * WOUT) + ho * WOUT;

    // ---- S1: bilinear meta per (tap,wo): packed addr/steps + factored bf16 wts ----
    for (int q = tid; q < KK * 64; q += 256) {
        int k  = q >> 6;
        int wo = q & 63;
        float dy = off_n[(2 * k) * (HOUT * WOUT) + wo];
        float dx = off_n[(2 * k + 1) * (HOUT * WOUT) + wo];
        int kh = (k * 171) >> 9;                       // k/3 for k<9
        int kw = k - 3 * kh;
        float py = (float)(ho + kh) + dy;
        float px = (float)(wo + kw) + dx;
        float y0f = floorf(py), x0f = floorf(px);
        float fy = py - y0f, fx = px - x0f;
        int y0 = (int)y0f, x0 = (int)x0f;
        int y1 = y0 + 1,   x1 = x0 + 1;
        float vy0 = (y0 >= 0 && y0 < HIN) ? 1.f : 0.f;
        float vy1 = (y1 >= 0 && y1 < HIN) ? 1.f : 0.f;
        float vx0 = (x0 >= 0 && x0 < WIN) ? 1.f : 0.f;
        float vx1 = (x1 >= 0 && x1 < WIN) ? 1.f : 0.f;
        int y0c = min(max(y0, 0), HIN - 1), y1c = min(max(y1, 0), HIN - 1);
        int x0c = min(max(x0, 0), WIN - 1), x1c = min(max(x1, 0), WIN - 1);
        int a00 = (y0c * WIN + x0c) * CIN;             // <2^19
        int sx  = x1c - x0c;                           // 0/1
        int sy  = y1c - y0c;                           // 0/1
        sAv[q] = a00 | (sx << 20) | (sy << 21);
        float ax0 = vx0 * (1.f - fx), ax1 = vx1 * fx;
        float ay0 = vy0 * (1.f - fy), ay1 = vy1 * fy;
        sAw[q] = make_int2((int)pkbf(ax0, ax1), (int)pkbf(ay0, ay1));
    }
    __syncthreads();

    f32x4 acc[4];
#pragma unroll
    for (int rt = 0; rt < 4; ++rt) acc[rt] = (f32x4){0.f, 0.f, 0.f, 0.f};

    const int c0  = (lane & 7) * 8;                    // 8 bf16 channels per lane
    const int grp = lane >> 3;                         // pair-slot within batch of 8
    const int h   = lane >> 4;

    // pair index J=0..5: p = wv*48 + (J>>1)*16 + (J&1)*8 + grp
#define LOADP(G, KB, J) do {                                           \
        int p_ = wv * 48 + ((J) >> 1) * 16 + ((J) & 1) * 8 + grp;      \
        int q_ = (KB) * 192 + p_;                                      \
        int av_ = sAv[q_];                                             \
        G.aw = sAw[q_];                                                \
        int a_  = (av_ & 0xFFFFF) + c0;                                \
        int dx_ = (av_ >> 14) & 64;                                    \
        int dy_ = ((av_ >> 21) & 1) * (WIN * CIN);                     \
        G.u0 = *(const int4*)(nh + a_);                                \
        G.u1 = *(const int4*)(nh + a_ + dx_);                          \
        G.u2 = *(const int4*)(nh + a_ + dy_);                          \
        G.u3 = *(const int4*)(nh + a_ + dy_ + dx_);                    \
        G.p = p_;                                                      \
    } while (0)

#define PROCP(G) do {                                                  \
        f32x2 AX = up2((unsigned int)G.aw.x);                          \
        f32x2 AY = up2((unsigned int)G.aw.y);                          \
        f32x2 W00 = {AY.x * AX.x, AY.x * AX.x};                        \
        f32x2 W01 = {AY.x * AX.y, AY.x * AX.y};                        \
        f32x2 W10 = {AY.y * AX.x, AY.y * AX.x};                        \
        f32x2 W11 = {AY.y * AX.y, AY.y * AX.y};                        \
        int4 r_;                                                       \
        r_.x = (int)blend_word(G.u0.x, G.u1.x, G.u2.x, G.u3.x, W00, W01, W10, W11); \
        r_.y = (int)blend_word(G.u0.y, G.u1.y, G.u2.y, G.u3.y, W00, W01, W10, W11); \
        r_.z = (int)blend_word(G.u0.z, G.u1.z, G.u2.z, G.u3.z, W00, W01, W10, W11); \
        r_.w = (int)blend_word(G.u0.w, G.u1.w, G.u2.w, G.u3.w, W00, W01, W10, W11); \
        int k3_ = G.p >> 6, wo_ = G.p & 63;                            \
        int sl_ = (k3_ * 8 + (lane & 7)) ^ (wo_ & 7);                  \
        *(int4*)(smS + wo_ * 384 + (sl_ << 4)) = r_;                   \
    } while (0)

    GB a0, a1;
    LOADP(a0, 0, 0);                                   // prologue: first pair in flight

#pragma unroll
    for (int kb = 0; kb < 3; ++kb) {
        // B-fragments for this kb: 6 contiguous 1KB wave-loads, in flight during gather
        bf16x8 breg[6];
#pragma unroll
        for (int ks = 0; ks < 6; ++ks)
            breg[ks] = *(const bf16x8*)(wF + (((wv * 18 + kb * 6 + ks) << 6) + lane) * 8);

        // ---- pipelined gather: load pair j+1 while blending pair j ----
        LOADP(a1, kb, 1); PROCP(a0);
        LOADP(a0, kb, 2); PROCP(a1);
        LOADP(a1, kb, 3); PROCP(a0);
        LOADP(a0, kb, 4); PROCP(a1);
        LOADP(a1, kb, 5); PROCP(a0);
        PROCP(a1);
        __syncthreads();

        if (kb < 2) LOADP(a0, kb + 1, 0);              // next kb's first pair rides under GEMM

        // ---- GEMM: A (all 64 rows) from swizzled LDS, B from regs ----
#pragma unroll
        for (int rt = 0; rt < 4; ++rt) {
            const int row = rt * 16 + (lane & 15);
#pragma unroll
            for (int ks = 0; ks < 6; ++ks) {
                int aslot = (ks * 4 + h) ^ (row & 7);
                bf16x8 af = *(const bf16x8*)(smS + row * 384 + (aslot << 4));
                acc[rt] = __builtin_amdgcn_mfma_f32_16x16x32_bf16(af, breg[ks], acc[rt], 0, 0, 0);
            }
        }
        __syncthreads();                               // smS reused next kb
    }
#undef LOADP
#undef PROCP

    // ---- epilogue: transpose through LDS for coalesced stores ----
    float* red = (float*)sm;                           // [64 couts][65] = 16640 B
#pragma unroll
    for (int rt = 0; rt < 4; ++rt)
#pragma unroll
        for (int r = 0; r < 4; ++r)
            red[(16 * wv + (lane & 15)) * 65 + (16 * rt + h * 4 + r)] = acc[rt][r];
    __syncthreads();
    float* op = out + (size_t)(n * COUT) * (HOUT * WOUT) + ho * WOUT + lane;
#pragma unroll
    for (int j = 0; j < 16; ++j) {
        int co = wv * 16 + j;
        op[(size_t)co * (HOUT * WOUT)] = red[co * 65 + lane];
    }
}

// ---------------- fallback (R2 path) if ws too small ----------------
__global__ __launch_bounds__(256) void repack_w_kernel(const float* __restrict__ w,
                                                       float* __restrict__ wT) {
    int i = blockIdx.x * 256 + threadIdx.x;
    if (i >= KK * CIN * COUT) return;
    int co = i & 63; int t = i >> 6;
    int c = t & 63;  int k = t >> 6;
    wT[i] = w[(co * CIN + c) * KK + k];
}

__global__ __launch_bounds__(256) void dconv_kernel(const float* __restrict__ inp,
                                                    const float* __restrict__ off,
                                                    const float* __restrict__ wT,
                                                    float* __restrict__ out) {
    const int tid = threadIdx.x;
    const int wo  = tid & 63;
    const int g   = tid >> 6;
    const int p   = blockIdx.x;
    const int logical = (p & (NXCD - 1)) * (NB * HOUT / NXCD) + (p >> 3);
    const int n   = logical >> 6;
    const int ho  = logical & 63;
    const int cbase = __builtin_amdgcn_readfirstlane(g << 4);
    float acc[COUT];
#pragma unroll
    for (int i = 0; i < COUT; ++i) acc[i] = 0.f;
    const float* inp_n = inp + n * (CIN * HIN * WIN);
    const float* off_p = off + ((n * (2 * KK)) * HOUT + ho) * WOUT + wo;
#pragma unroll 1
    for (int k = 0; k < KK; ++k) {
        float dy = off_p[(2 * k) * (HOUT * WOUT)];
        float dx = off_p[(2 * k + 1) * (HOUT * WOUT)];
        float py = (float)(ho + k / 3) + dy;
        float px = (float)(wo + k % 3) + dx;
        float y0f = floorf(py), x0f = floorf(px);
        float fy = py - y0f, fx = px - x0f;
        int y0 = (int)y0f, x0 = (int)x0f;
        int y1 = y0 + 1,   x1 = x0 + 1;
        float vy0 = (y0 >= 0 && y0 < HIN) ? 1.f : 0.f;
        float vy1 = (y1 >= 0 && y1 < HIN) ? 1.f : 0.f;
        float vx0 = (x0 >= 0 && x0 < WIN) ? 1.f : 0.f;
        float vx1 = (x1 >= 0 && x1 < WIN) ? 1.f : 0.f;
        int y0c = min(max(y0, 0), HIN - 1), y1c = min(max(y1, 0), HIN - 1);
        int x0c = min(max(x0, 0), WIN - 1), x1c = min(max(x1, 0), WIN - 1);
        int o00 = y0c * WIN + x0c, o01 = y0c * WIN + x1c;
        int o10 = y1c * WIN + x0c, o11 = y1c * WIN + x1c;
        float w00 = (1.f - fy) * (1.f - fx) * vy0 * vx0;
        float w01 = (1.f - fy) * fx * vy0 * vx1;
        float w10 = fy * (1.f - fx) * vy1 * vx0;
        float w11 = fy * fx * vy1 * vx1;
        const float* pc   = inp_n + cbase * (HIN * WIN);
        const float* wrow = wT + ((k * CIN + cbase) << 6);
#pragma unroll 4
        for (int c = 0; c < 16; ++c) {
            float v = w00 * pc[o00] + w01 * pc[o01] + w10 * pc[o10] + w11 * pc[o11];
#pragma unroll
            for (int co = 0; co < COUT; ++co) acc[co] = fmaf(v, wrow[co], acc[co]);
            pc += HIN * WIN; wrow += COUT;
        }
    }
    __shared__ float redf[COUT * WOUT];
    for (int i = tid; i < COUT * WOUT; i += 256) redf[i] = 0.f;
    __syncthreads();
#pragma unroll
    for (int co = 0; co < COUT; ++co) atomicAdd(&redf[co * WOUT + wo], acc[co]);
    __syncthreads();
    float* out_p = out + (n * COUT * HOUT + ho) * WOUT;
    for (int i = tid; i < COUT * WOUT; i += 256) {
        int co = i >> 6, w2 = i & 63;
        out_p[co * (HOUT * WOUT) + w2] = redf[i];
    }
}

extern "C" void kernel_launch(void* const* d_in, const int* in_sizes, int n_in,
                              void* d_out, int out_size, void* d_ws, size_t ws_size,
                              hipStream_t stream) {
    const float* inp = (const float*)d_in[0];
    const float* off = (const float*)d_in[1];
    const float* w   = (const float*)d_in[2];
    float* out = (float*)d_out;

    const size_t nhwc_bytes = (size_t)NB * HIN * WIN * CIN * 2;   // bf16: 8,921,088
    const size_t wF_bytes   = (size_t)4 * 18 * 64 * 8 * 2;        // 73,728

    if (ws_size >= nhwc_bytes + wF_bytes) {
        unsigned short* nhwc = (unsigned short*)d_ws;
        unsigned short* wF   = (unsigned short*)((char*)d_ws + nhwc_bytes);
        repack_all<<<NB * HIN + 144, 256, 0, stream>>>(inp, w, nhwc, wF);
        dconv8<<<NB * HOUT, 256, 0, stream>>>(nhwc, off, wF, out);
    } else {
        float* wT = (float*)d_ws;
        repack_w_kernel<<<(KK * CIN * COUT + 255) / 256, 256, 0, stream>>>(w, wT);
        dconv_kernel<<<NB * HOUT, 256, 0, stream>>>(inp, off, wT, out);
    }
}

// Round 10
// 30.948 us; speedup vs baseline: 2.3837x; 1.1116x over previous
//
#include <hip/hip_runtime.h>
#include <hip/hip_bf16.h>

#define NB    16
#define CIN   64
#define COUT  64
#define HIN   66
#define WIN   66
#define HOUT  64
#define WOUT  64
#define KK    9
#define NXCD  8

typedef __attribute__((ext_vector_type(8))) short bf16x8;
typedef __attribute__((ext_vector_type(4))) float f32x4;
typedef __attribute__((ext_vector_type(2))) float f32x2;

static __device__ __forceinline__ unsigned int pkbf(float lo, float hi) {
    union { __hip_bfloat162 b; unsigned int u; } x;
    x.b = __float22bfloat162_rn(make_float2(lo, hi));   // v_cvt_pk_bf16_f32
    return x.u;
}

static __device__ __forceinline__ f32x2 up2(unsigned int w) {
    f32x2 r;
    r.x = __uint_as_float(w << 16);
    r.y = __uint_as_float(w & 0xFFFF0000u);
    return r;
}

static __device__ __forceinline__ unsigned int blend_word(unsigned int d00, unsigned int d01,
                                                          unsigned int d10, unsigned int d11,
                                                          f32x2 W00, f32x2 W01, f32x2 W10, f32x2 W11) {
    f32x2 v = W00 * up2(d00);           // v_pk_mul/_fma_f32
    v += W01 * up2(d01);
    v += W10 * up2(d10);
    v += W11 * up2(d11);
    return pkbf(v.x, v.y);
}

// ---------------- merged repack: NCHW f32 -> NHWC bf16  +  W -> fragment-major bf16 ----------------
// Image blocks are XCD-affinity swizzled: physical p runs on XCD p%8; we assign
// XCD x the rows of images 2x,2x+1 — the same images dconv's chunked swizzle
// consumes on XCD x, so the bf16 tile is produced into the consumer's L2.
__global__ __launch_bounds__(256) void repack_all(const float* __restrict__ in,
                                                  const float* __restrict__ w,
                                                  unsigned short* __restrict__ nhwc,
                                                  unsigned short* __restrict__ wF) {
    int b = blockIdx.x;
    if (b < NB * HIN) {
        int l = (b & 7) * (NB * HIN / 8) + (b >> 3);    // 1056 = 8*132, bijective
        int n = l / HIN, y = l % HIN;
        __shared__ float buf[CIN * 67];
        const float* src = in + (size_t)(n * CIN) * HIN * WIN + y * WIN;
        for (int i = threadIdx.x; i < CIN * WIN; i += 256) {
            int c = i / WIN, x = i - c * WIN;
            buf[c * 67 + x] = src[c * (HIN * WIN) + x];
        }
        __syncthreads();
        int2* dst = (int2*)(nhwc + (size_t)((n * HIN + y) * WIN) * CIN);
        for (int i = threadIdx.x; i < WIN * (CIN / 4); i += 256) {
            int x = i >> 4, c4 = (i & 15) * 4;          // 4 channels per 8B store
            dst[x * 16 + (c4 >> 2)] =
                make_int2((int)pkbf(buf[c4 * 67 + x], buf[(c4 + 1) * 67 + x]),
                          (int)pkbf(buf[(c4 + 2) * 67 + x], buf[(c4 + 3) * 67 + x]));
        }
    } else {
        int i = (b - NB * HIN) * 256 + threadIdx.x;
        if (i >= 4 * 18 * 64 * 8) return;
        int j    = i & 7;
        int t    = i >> 3;
        int lane = t & 63;  t >>= 6;
        int ksg  = t % 18;
        int ct   = t / 18;
        int kb = ksg / 6, ks = ksg % 6;
        int klocal = ks * 32 + (lane >> 4) * 8 + j;
        int tap = kb * 3 + (klocal >> 6);
        int cin = klocal & 63;
        int cout = ct * 16 + (lane & 15);
        wF[i] = (unsigned short)(pkbf(w[(cout * CIN + cin) * KK + tap], 0.f) & 0xFFFF);
    }
}

struct GB { int4 u0, u1, u2, u3; int q; };              // 17 VGPR

// ---------------- main: implicit-GEMM deformable conv via MFMA ----------------
__global__ __launch_bounds__(256, 4) void dconv9(const unsigned short* __restrict__ nhwc,
                                                 const float* __restrict__ off,
                                                 const unsigned short* __restrict__ wF,
                                                 float* __restrict__ out) {
    __shared__ __align__(16) char sm[31488];
    char* smS = sm;                                    // 24576: sampled tile (swizzled)
    int*  sAv = (int*)(sm + 24576);                    // 576 packed addrs      (2304 B)
    int2* sAw = (int2*)(sm + 26880);                   // 576 bf16x4 bilinear wts (4608 B)

    const int tid  = threadIdx.x;
    const int lane = tid & 63;
    const int wv   = tid >> 6;
    const int p0 = blockIdx.x;
    const int logical = (p0 & (NXCD - 1)) * (NB * HOUT / NXCD) + (p0 >> 3);
    const int n  = logical >> 6;
    const int ho = logical & 63;

    const unsigned short* nh = nhwc + (size_t)n * (HIN * WIN * CIN);
    const float* off_n = off + (size_t)n * (2 * KK * HOUT * WOUT) + ho * WOUT;

    // ---- S1: bilinear meta per (tap,wo): packed addr/steps + factored bf16 wts ----
    for (int q = tid; q < KK * 64; q += 256) {
        int k  = q >> 6;
        int wo = q & 63;
        float dy = off_n[(2 * k) * (HOUT * WOUT) + wo];
        float dx = off_n[(2 * k + 1) * (HOUT * WOUT) + wo];
        int kh = (k * 171) >> 9;                       // k/3 for k<9
        int kw = k - 3 * kh;
        float py = (float)(ho + kh) + dy;
        float px = (float)(wo + kw) + dx;
        float y0f = floorf(py), x0f = floorf(px);
        float fy = py - y0f, fx = px - x0f;
        int y0 = (int)y0f, x0 = (int)x0f;
        int y1 = y0 + 1,   x1 = x0 + 1;
        float vy0 = (y0 >= 0 && y0 < HIN) ? 1.f : 0.f;
        float vy1 = (y1 >= 0 && y1 < HIN) ? 1.f : 0.f;
        float vx0 = (x0 >= 0 && x0 < WIN) ? 1.f : 0.f;
        float vx1 = (x1 >= 0 && x1 < WIN) ? 1.f : 0.f;
        int y0c = min(max(y0, 0), HIN - 1), y1c = min(max(y1, 0), HIN - 1);
        int x0c = min(max(x0, 0), WIN - 1), x1c = min(max(x1, 0), WIN - 1);
        int a00 = (y0c * WIN + x0c) * CIN;             // <2^19
        int sx  = x1c - x0c;                           // 0/1
        int sy  = y1c - y0c;                           // 0/1
        sAv[q] = a00 | (sx << 20) | (sy << 21);
        float ax0 = vx0 * (1.f - fx), ax1 = vx1 * fx;
        float ay0 = vy0 * (1.f - fy), ay1 = vy1 * fy;
        sAw[q] = make_int2((int)pkbf(ax0, ax1), (int)pkbf(ay0, ay1));
    }
    __syncthreads();

    f32x4 acc[4];
#pragma unroll
    for (int rt = 0; rt < 4; ++rt) acc[rt] = (f32x4){0.f, 0.f, 0.f, 0.f};

    const int c0  = (lane & 7) * 8;                    // 8 bf16 channels per lane
    const int grp = lane >> 3;                         // pair-slot within batch of 8
    const int h   = lane >> 4;

    // pair index J=0..5: p = wv*48 + (J>>1)*16 + (J&1)*8 + grp; q = KB*192 + p
#define LOADP(G, KB, J) do {                                           \
        int q_ = (KB) * 192 + wv * 48 + ((J) >> 1) * 16 + ((J) & 1) * 8 + grp; \
        int av_ = sAv[q_];                                             \
        int a_  = (av_ & 0xFFFFF) + c0;                                \
        int dx_ = (av_ >> 14) & 64;                                    \
        int dy_ = ((av_ >> 21) & 1) * (WIN * CIN);                     \
        G.u0 = *(const int4*)(nh + a_);                                \
        G.u1 = *(const int4*)(nh + a_ + dx_);                          \
        G.u2 = *(const int4*)(nh + a_ + dy_);                          \
        G.u3 = *(const int4*)(nh + a_ + dy_ + dx_);                    \
        G.q = q_;                                                      \
    } while (0)

#define PROCP(G) do {                                                  \
        int2 aw_ = sAw[G.q];                                           \
        f32x2 AX = up2((unsigned int)aw_.x);                           \
        f32x2 AY = up2((unsigned int)aw_.y);                           \
        f32x2 W00 = {AY.x * AX.x, AY.x * AX.x};                        \
        f32x2 W01 = {AY.x * AX.y, AY.x * AX.y};                        \
        f32x2 W10 = {AY.y * AX.x, AY.y * AX.x};                        \
        f32x2 W11 = {AY.y * AX.y, AY.y * AX.y};                        \
        int4 r_;                                                       \
        r_.x = (int)blend_word(G.u0.x, G.u1.x, G.u2.x, G.u3.x, W00, W01, W10, W11); \
        r_.y = (int)blend_word(G.u0.y, G.u1.y, G.u2.y, G.u3.y, W00, W01, W10, W11); \
        r_.z = (int)blend_word(G.u0.z, G.u1.z, G.u2.z, G.u3.z, W00, W01, W10, W11); \
        r_.w = (int)blend_word(G.u0.w, G.u1.w, G.u2.w, G.u3.w, W00, W01, W10, W11); \
        int wo_ = G.q & 63;                                            \
        int k3_ = (G.q >> 6) % 3;                                      \
        int sl_ = (k3_ * 8 + (lane & 7)) ^ (wo_ & 7);                  \
        *(int4*)(smS + wo_ * 384 + (sl_ << 4)) = r_;                   \
    } while (0)

    GB a0, a1, a2;
    LOADP(a0, 0, 0);                                   // prologue: 2 pairs in flight
    LOADP(a1, 0, 1);

#pragma unroll
    for (int kb = 0; kb < 3; ++kb) {
        // B-fragments for this kb: 6 contiguous 1KB wave-loads, in flight through gather
        bf16x8 breg[6];
#pragma unroll
        for (int ks = 0; ks < 6; ++ks)
            breg[ks] = *(const bf16x8*)(wF + (((wv * 18 + kb * 6 + ks) << 6) + lane) * 8);

        // ---- depth-2 pipelined gather: loads lead their blend by 2 groups ----
        LOADP(a2, kb, 2); PROCP(a0);
        LOADP(a0, kb, 3); PROCP(a1);
        LOADP(a1, kb, 4); PROCP(a2);
        LOADP(a2, kb, 5); PROCP(a0);
        PROCP(a1);
        PROCP(a2);
        __syncthreads();

        if (kb < 2) {                                  // next kb's lead pairs ride under GEMM
            LOADP(a0, kb + 1, 0);
            LOADP(a1, kb + 1, 1);
        }

        // ---- GEMM: A (all 64 rows) from swizzled LDS, B from regs ----
#pragma unroll
        for (int rt = 0; rt < 4; ++rt) {
            const int row = rt * 16 + (lane & 15);
#pragma unroll
            for (int ks = 0; ks < 6; ++ks) {
                int aslot = (ks * 4 + h) ^ (row & 7);
                bf16x8 af = *(const bf16x8*)(smS + row * 384 + (aslot << 4));
                acc[rt] = __builtin_amdgcn_mfma_f32_16x16x32_bf16(af, breg[ks], acc[rt], 0, 0, 0);
            }
        }
        __syncthreads();                               // smS reused next kb
    }
#undef LOADP
#undef PROCP

    // ---- epilogue: transpose through LDS for coalesced stores ----
    float* red = (float*)sm;                           // [64 couts][65] = 16640 B
#pragma unroll
    for (int rt = 0; rt < 4; ++rt)
#pragma unroll
        for (int r = 0; r < 4; ++r)
            red[(16 * wv + (lane & 15)) * 65 + (16 * rt + h * 4 + r)] = acc[rt][r];
    __syncthreads();
    float* op = out + (size_t)(n * COUT) * (HOUT * WOUT) + ho * WOUT + lane;
#pragma unroll
    for (int j = 0; j < 16; ++j) {
        int co = wv * 16 + j;
        op[(size_t)co * (HOUT * WOUT)] = red[co * 65 + lane];
    }
}

// ---------------- fallback (R2 path) if ws too small ----------------
__global__ __launch_bounds__(256) void repack_w_kernel(const float* __restrict__ w,
                                                       float* __restrict__ wT) {
    int i = blockIdx.x * 256 + threadIdx.x;
    if (i >= KK * CIN * COUT) return;
    int co = i & 63; int t = i >> 6;
    int c = t & 63;  int k = t >> 6;
    wT[i] = w[(co * CIN + c) * KK + k];
}

__global__ __launch_bounds__(256) void dconv_kernel(const float* __restrict__ inp,
                                                    const float* __restrict__ off,
                                                    const float* __restrict__ wT,
                                                    float* __restrict__ out) {
    const int tid = threadIdx.x;
    const int wo  = tid & 63;
    const int g   = tid >> 6;
    const int p   = blockIdx.x;
    const int logical = (p & (NXCD - 1)) * (NB * HOUT / NXCD) + (p >> 3);
    const int n   = logical >> 6;
    const int ho  = logical & 63;
    const int cbase = __builtin_amdgcn_readfirstlane(g << 4);
    float acc[COUT];
#pragma unroll
    for (int i = 0; i < COUT; ++i) acc[i] = 0.f;
    const float* inp_n = inp + n * (CIN * HIN * WIN);
    const float* off_p = off + ((n * (2 * KK)) * HOUT + ho) * WOUT + wo;
#pragma unroll 1
    for (int k = 0; k < KK; ++k) {
        float dy = off_p[(2 * k) * (HOUT * WOUT)];
        float dx = off_p[(2 * k + 1) * (HOUT * WOUT)];
        float py = (float)(ho + k / 3) + dy;
        float px = (float)(wo + k % 3) + dx;
        float y0f = floorf(py), x0f = floorf(px);
        float fy = py - y0f, fx = px - x0f;
        int y0 = (int)y0f, x0 = (int)x0f;
        int y1 = y0 + 1,   x1 = x0 + 1;
        float vy0 = (y0 >= 0 && y0 < HIN) ? 1.f : 0.f;
        float vy1 = (y1 >= 0 && y1 < HIN) ? 1.f : 0.f;
        float vx0 = (x0 >= 0 && x0 < WIN) ? 1.f : 0.f;
        float vx1 = (x1 >= 0 && x1 < WIN) ? 1.f : 0.f;
        int y0c = min(max(y0, 0), HIN - 1), y1c = min(max(y1, 0), HIN - 1);
        int x0c = min(max(x0, 0), WIN - 1), x1c = min(max(x1, 0), WIN - 1);
        int o00 = y0c * WIN + x0c, o01 = y0c * WIN + x1c;
        int o10 = y1c * WIN + x0c, o11 = y1c * WIN + x1c;
        float w00 = (1.f - fy) * (1.f - fx) * vy0 * vx0;
        float w01 = (1.f - fy) * fx * vy0 * vx1;
        float w10 = fy * (1.f - fx) * vy1 * vx0;
        float w11 = fy * fx * vy1 * vx1;
        const float* pc   = inp_n + cbase * (HIN * WIN);
        const float* wrow = wT + ((k * CIN + cbase) << 6);
#pragma unroll 4
        for (int c = 0; c < 16; ++c) {
            float v = w00 * pc[o00] + w01 * pc[o01] + w10 * pc[o10] + w11 * pc[o11];
#pragma unroll
            for (int co = 0; co < COUT; ++co) acc[co] = fmaf(v, wrow[co], acc[co]);
            pc += HIN * WIN; wrow += COUT;
        }
    }
    __shared__ float redf[COUT * WOUT];
    for (int i = tid; i < COUT * WOUT; i += 256) redf[i] = 0.f;
    __syncthreads();
#pragma unroll
    for (int co = 0; co < COUT; ++co) atomicAdd(&redf[co * WOUT + wo], acc[co]);
    __syncthreads();
    float* out_p = out + (n * COUT * HOUT + ho) * WOUT;
    for (int i = tid; i < COUT * WOUT; i += 256) {
        int co = i >> 6, w2 = i & 63;
        out_p[co * (HOUT * WOUT) + w2] = redf[i];
    }
}

extern "C" void kernel_launch(void* const* d_in, const int* in_sizes, int n_in,
                              void* d_out, int out_size, void* d_ws, size_t ws_size,
                              hipStream_t stream) {
    const float* inp = (const float*)d_in[0];
    const float* off = (const float*)d_in[1];
    const float* w   = (const float*)d_in[2];
    float* out = (float*)d_out;

    const size_t nhwc_bytes = (size_t)NB * HIN * WIN * CIN * 2;   // bf16: 8,921,088
    const size_t wF_bytes   = (size_t)4 * 18 * 64 * 8 * 2;        // 73,728

    if (ws_size >= nhwc_bytes + wF_bytes) {
        unsigned short* nhwc = (unsigned short*)d_ws;
        unsigned short* wF   = (unsigned short*)((char*)d_ws + nhwc_bytes);
        repack_all<<<NB * HIN + 144, 256, 0, stream>>>(inp, w, nhwc, wF);
        dconv9<<<NB * HOUT, 256, 0, stream>>>(nhwc, off, wF, out);
    } else {
        float* wT = (float*)d_ws;
        repack_w_kernel<<<(KK * CIN * COUT + 255) / 256, 256, 0, stream>>>(w, wT);
        dconv_kernel<<<NB * HOUT, 256, 0, stream>>>(inp, off, wT, out);
    }
}